// Round 7
// baseline (4838.791 us; speedup 1.0000x reference)
//
#include <hip/hip_runtime.h>
#include <math.h>

// ---------------------------------------------------------------------------
// IPOT on MI355X — round 12.
// Math (exact, verified in R1-R11):
//   Cl = -C;  M_t = exp((t+1)*Cl)
//   row:  r_i = sum_j M_t(i,j) s_j ; a = 1/(n r)
//   col:  c_j = sum_i M_t(i,j) a_i ; b = 1/c (2^10 inj); s' = b^2/b_prev/1024
//   final G(A,B) = (1/(256*1024)) sum_k P(k,A) R(k,B)
// R12 (R11 proved RMW chains cheap; floor = sync HOP COUNT + k_gemm LDS-bound):
//   - k_ipot: tagged-data (sign-parity; partials > 0) per-WG slots, plain
//     stores, NO drain barrier. tid0 stores an OPTIMISTIC tagged hint flag
//     (unordered vs other threads' data). wave0 polls hints (parked economy,
//     anti-storm); after barrier, every thread one-shot-readbacks 32 slots
//     and VERIFIES TAGS itself (tags=truth), selective retry for stragglers.
//     Removes drain RT + 1 barrier (4 -> 3). vals[32]+E[32] fit the 128-VGPR
//     budget forced by the >80KB LDS pad (R10 mechanism) -> no spill.
//   - k_gemm: 128x64 tile, 256 thr, 8x4 micro (128 WGs): 4x arithmetic
//     intensity per LDS byte vs 64x64/2x2. Staging keeps (row,kq) partials,
//     8-lane xor tree, ascending-k single-acc dots -> C BIT-IDENTICAL.
// ---------------------------------------------------------------------------

#define NWG 32
#define TPB 1024
#define NIT 50

typedef unsigned long long ull;

// ws offsets in floats
constexpr int CL_OFF   = 0;                           // -C [1024*1024]
constexpr int CVEC_OFF = 1024 * 1024;                 // [3][NWG][1024] tagged
constexpr int FLG_OFF  = CVEC_OFF + 3 * NWG * 1024;   // [3][NWG] tagged hints
// total ~ 4.6 MB

// ---------------- C = 1 - xhat yhat^T (norms fused) ; Cl = -C ---------------
__global__ __launch_bounds__(256, 1) void k_gemm(const float* __restrict__ X,
                                                 const float* __restrict__ Y,
                                                 float* __restrict__ ws) {
    __shared__ float As[32][132];   // X-tile, k-major, 128 rows
    __shared__ float Bs[32][68];    // Y-tile, k-major, 64 rows
    __shared__ float nX[128], nY[64];
    float* Cl = ws + CL_OFF;

    int tid = threadIdx.x;
    int tx = tid & 15, ty = tid >> 4;       // cols 4*tx, rows 8*ty
    int bx = blockIdx.x, by = blockIdx.y;   // bx 0..15 (64 cols), by 0..7 (128 rows)
    int sr = tid >> 3;                      // 0..31
    int kq = (tid & 7) * 4;                 // 0..28

    float acc[8][4] = {};
    float snx[4] = {0.f, 0.f, 0.f, 0.f};
    float sny0 = 0.f, sny1 = 0.f;
    for (int k0 = 0; k0 < 512; k0 += 32) {
        // stage X rows sr+32m (m<4) and Y rows sr, sr+32 at kq chunk
#pragma unroll
        for (int m = 0; m < 4; ++m) {
            int r = sr + 32 * m;
            float4 v = *(const float4*)(X + (size_t)(by * 128 + r) * 512 + k0 + kq);
            snx[m] += v.x * v.x + v.y * v.y + v.z * v.z + v.w * v.w;
            As[kq + 0][r] = v.x; As[kq + 1][r] = v.y;
            As[kq + 2][r] = v.z; As[kq + 3][r] = v.w;
        }
        {
            float4 v = *(const float4*)(Y + (size_t)(bx * 64 + sr) * 512 + k0 + kq);
            sny0 += v.x * v.x + v.y * v.y + v.z * v.z + v.w * v.w;
            Bs[kq + 0][sr] = v.x; Bs[kq + 1][sr] = v.y;
            Bs[kq + 2][sr] = v.z; Bs[kq + 3][sr] = v.w;
            float4 w = *(const float4*)(Y + (size_t)(bx * 64 + sr + 32) * 512 + k0 + kq);
            sny1 += w.x * w.x + w.y * w.y + w.z * w.z + w.w * w.w;
            Bs[kq + 0][sr + 32] = w.x; Bs[kq + 1][sr + 32] = w.y;
            Bs[kq + 2][sr + 32] = w.z; Bs[kq + 3][sr + 32] = w.w;
        }
        __syncthreads();
#pragma unroll
        for (int kk = 0; kk < 32; ++kk) {
            float4 a0 = *(const float4*)&As[kk][8 * ty];
            float4 a1 = *(const float4*)&As[kk][8 * ty + 4];
            float4 b0 = *(const float4*)&Bs[kk][4 * tx];
            float av[8] = {a0.x, a0.y, a0.z, a0.w, a1.x, a1.y, a1.z, a1.w};
            float bw[4] = {b0.x, b0.y, b0.z, b0.w};
#pragma unroll
            for (int r = 0; r < 8; ++r)
#pragma unroll
                for (int q = 0; q < 4; ++q) acc[r][q] += av[r] * bw[q];
        }
        __syncthreads();
    }
#pragma unroll
    for (int m2 = 1; m2 < 8; m2 <<= 1) {
#pragma unroll
        for (int m = 0; m < 4; ++m) snx[m] += __shfl_xor(snx[m], m2, 64);
        sny0 += __shfl_xor(sny0, m2, 64);
        sny1 += __shfl_xor(sny1, m2, 64);
    }
    if ((tid & 7) == 0) {
#pragma unroll
        for (int m = 0; m < 4; ++m) nX[sr + 32 * m] = snx[m];
        nY[sr] = sny0; nY[sr + 32] = sny1;
    }
    __syncthreads();

    float vy[4];
#pragma unroll
    for (int q = 0; q < 4; ++q) vy[q] = 1.0f / sqrtf(nY[4 * tx + q]);
    int i0 = by * 128 + 8 * ty, j0 = bx * 64 + 4 * tx;
#pragma unroll
    for (int r = 0; r < 8; ++r) {
        float vx = 1.0f / sqrtf(nX[8 * ty + r]);
        float4 o;
        o.x = acc[r][0] * vx * vy[0] - 1.0f;  // Cl = dot - 1 = -C
        o.y = acc[r][1] * vx * vy[1] - 1.0f;
        o.z = acc[r][2] * vx * vy[2] - 1.0f;
        o.w = acc[r][3] * vx * vy[3] - 1.0f;
        *(float4*)(Cl + (size_t)(i0 + r) * 1024 + j0) = o;
    }
}

// ---------------------- persistent IPOT iteration --------------------------
__global__ __launch_bounds__(1024)
void k_ipot(float* __restrict__ ws, float* __restrict__ out) {
    __shared__ float sLp[1056];        // s (loop) / b (epilogue): [u][l], stride 66
    __shared__ float buf[16 * 1056];   // col partials [wave][u*66+lane]; epi Ps/Rs
    __shared__ float twv[16];
    __shared__ float pad[2600];        // LDS > 80KB -> 1 WG/CU -> 128-VGPR budget

    const int g = blockIdx.x, tid = threadIdx.x;
    const int rs = tid >> 6, lane = tid & 63;   // wave id (0..15) / lane
    const int uo = tid & 15, lo = tid >> 4;     // owned col tid = lo*16+uo
    float* Cl   = ws + CL_OFF;
    float* cvec = ws + CVEC_OFF;
    float* flg  = ws + FLG_OFF;

    pad[tid & 2047] = 0.0f;  // keep pad allocated; read (exact +0.0) at end

    // thread owns rows g*32 + rs*2 + i (i<2), cols lane*16 + u (u<16)
    const float* csrc0 = Cl + (size_t)(g * 32 + rs * 2 + 0) * 1024 + lane * 16;
    const float* csrc1 = csrc0 + 1024;

    float E[2][16];
    float p0 = 0.0f, p1 = 0.0f;   // rowsum(Cl) for epilogue (C not kept)
#pragma unroll
    for (int q = 0; q < 4; ++q) {
        float4 c0 = *(const float4*)(csrc0 + 4 * q);
        float4 c1 = *(const float4*)(csrc1 + 4 * q);
        p0 += c0.x + c0.y + c0.z + c0.w;
        p1 += c1.x + c1.y + c1.z + c1.w;
        E[0][4 * q + 0] = __expf(c0.x); E[0][4 * q + 1] = __expf(c0.y);
        E[0][4 * q + 2] = __expf(c0.z); E[0][4 * q + 3] = __expf(c0.w);
        E[1][4 * q + 0] = __expf(c1.x); E[1][4 * q + 1] = __expf(c1.y);
        E[1][4 * q + 2] = __expf(c1.z); E[1][4 * q + 3] = __expf(c1.w);
    }

    float bv = 1.0f;            // b_prev for owned col (= tid)
    float a0 = 0.0f, a1 = 0.0f; // this wave's row scalings (all lanes)

    for (int t = 0; t < NIT; ++t) {
        float sval;
        if (t == 0) {
            sval = 1.0f / 1024.0f;
        } else {
            const int bsel = (t - 1) % 3;
            const bool expneg = ((t - 1) & 1) == 0;  // even iter stored -v
            // wave 0: optimistic hint poll (parked economy); tags are truth
            if (rs == 0) {
                const float* fb = flg + bsel * NWG + (lane & 31);
                long gd = 0;
                for (;;) {
                    float v = __hip_atomic_load(fb, __ATOMIC_RELAXED,
                                                __HIP_MEMORY_SCOPE_AGENT);
                    bool ok = expneg ? (v < 0.0f) : (v > 0.0f);
                    if (__all(ok)) break;
                    if (++gd > 2000000) break;  // anti-hang bailout
                    __builtin_amdgcn_s_sleep(1);
                }
            }
            __syncthreads();
            // one-shot tagged readback of own column; selective retry
            const float* rb = cvec + bsel * (NWG * 1024) + tid;
            float vals[NWG];
            unsigned pend = 0xffffffffu;
            long gd = 0;
            for (;;) {
#pragma unroll
                for (int s2 = 0; s2 < NWG; ++s2) {
                    if (pend & (1u << s2)) {
                        float v = __hip_atomic_load(rb + s2 * 1024, __ATOMIC_RELAXED,
                                                    __HIP_MEMORY_SCOPE_AGENT);
                        unsigned bits = __float_as_uint(v);
                        bool ok = expneg ? (bits > 0x80000000u)
                                         : (bits != 0u && bits < 0x80000000u);
                        if (ok) { vals[s2] = v; pend &= ~(1u << s2); }
                    }
                }
                if (!pend) break;
                if (++gd > 500000) break;  // anti-hang bailout
                __builtin_amdgcn_s_sleep(1);
            }
            float ssum = 0.0f;
#pragma unroll
            for (int s2 = 0; s2 < NWG; ++s2) ssum += vals[s2];  // ascending order
            float c = expneg ? -ssum : ssum;
            float b = 1.0f / c;
            sval = b * b / bv * (1.0f / 1024.0f);  // 2^-10 inj
            bv = b;
        }
        sLp[uo * 66 + lo] = sval;   // s for col tid at [tid&15][tid>>4]
        __syncthreads();

        // row phase: rp[i] = sum_u E[i][u] * s[lane*16+u]; xor-reduce -> all lanes
        float sv[16];
#pragma unroll
        for (int u = 0; u < 16; ++u) sv[u] = sLp[u * 66 + lane];
        float rp0 = 0.0f, rp1 = 0.0f;
#pragma unroll
        for (int u = 0; u < 16; ++u) {
            rp0 += E[0][u] * sv[u];
            rp1 += E[1][u] * sv[u];
        }
#pragma unroll
        for (int m = 1; m < 64; m <<= 1) {
            rp0 += __shfl_xor(rp0, m, 64);
            rp1 += __shfl_xor(rp1, m, 64);
        }
        a0 = 1.0f / (1024.0f * rp0);
        a1 = 1.0f / (1024.0f * rp1);

        // col phase: this wave's 2-row partials for its 16 cols (padded layout)
#pragma unroll
        for (int u = 0; u < 16; ++u)
            buf[rs * 1056 + u * 66 + lane] = E[0][u] * a0 + E[1][u] * a1;
        __syncthreads();

        // owner (col tid): sum 16 wave-partials, TAGGED store + hint (no drain)
        float csum = 0.0f;
#pragma unroll
        for (int w = 0; w < 16; ++w) csum += buf[w * 1056 + uo * 66 + lo];
        float tagged = (t & 1) ? csum : -csum;  // odd -> +, even -> -
        __hip_atomic_store(cvec + (t % 3) * (NWG * 1024) + g * 1024 + tid, tagged,
                           __ATOMIC_RELAXED, __HIP_MEMORY_SCOPE_AGENT);
        if (tid == 0)
            __hip_atomic_store(flg + (t % 3) * NWG + g, (t & 1) ? 1.0f : -1.0f,
                               __ATOMIC_RELAXED, __HIP_MEMORY_SCOPE_AGENT);

        // recompute E for next round: reload Cl (L2-hot) in the skew shadow
        if (t < NIT - 1) {
            const float kf = (float)(t + 2);
#pragma unroll
            for (int q = 0; q < 4; ++q) {
                float4 c0 = *(const float4*)(csrc0 + 4 * q);
                float4 c1 = *(const float4*)(csrc1 + 4 * q);
                E[0][4 * q + 0] = __expf(kf * c0.x); E[0][4 * q + 1] = __expf(kf * c0.y);
                E[0][4 * q + 2] = __expf(kf * c0.z); E[0][4 * q + 3] = __expf(kf * c0.w);
                E[1][4 * q + 0] = __expf(kf * c1.x); E[1][4 * q + 1] = __expf(kf * c1.y);
                E[1][4 * q + 2] = __expf(kf * c1.z); E[1][4 * q + 3] = __expf(kf * c1.w);
            }
        }
    }

    // ------------- epilogue: E = exp(50*Cl), a0/a1 = round-49 a -------------
    {
        const int bsel = (NIT - 1) % 3;      // iter 49, odd -> positive tags
        if (rs == 0) {
            const float* fb = flg + bsel * NWG + (lane & 31);
            long gd = 0;
            for (;;) {
                float v = __hip_atomic_load(fb, __ATOMIC_RELAXED,
                                            __HIP_MEMORY_SCOPE_AGENT);
                if (__all(v > 0.0f)) break;
                if (++gd > 2000000) break;
                __builtin_amdgcn_s_sleep(1);
            }
        }
        __syncthreads();
        const float* rb = cvec + bsel * (NWG * 1024) + tid;
        float vals[NWG];
        unsigned pend = 0xffffffffu;
        long gd = 0;
        for (;;) {
#pragma unroll
            for (int s2 = 0; s2 < NWG; ++s2) {
                if (pend & (1u << s2)) {
                    float v = __hip_atomic_load(rb + s2 * 1024, __ATOMIC_RELAXED,
                                                __HIP_MEMORY_SCOPE_AGENT);
                    unsigned bits = __float_as_uint(v);
                    if (bits != 0u && bits < 0x80000000u) {
                        vals[s2] = v; pend &= ~(1u << s2);
                    }
                }
            }
            if (!pend) break;
            if (++gd > 500000) break;
            __builtin_amdgcn_s_sleep(1);
        }
        float ssum = 0.0f;
#pragma unroll
        for (int s2 = 0; s2 < NWG; ++s2) ssum += vals[s2];
        sLp[uo * 66 + lo] = 1.0f / ssum;   // b for col tid
    }
    __syncthreads();

    // P(k,A=lane) and R(k,B=lane) for this thread's 2 rows (A-block == lane)
    float* Ps = buf;          // [32][64]
    float* Rs = buf + 2048;   // [32][64]
    float bl[16];
#pragma unroll
    for (int u = 0; u < 16; ++u) bl[u] = sLp[u * 66 + lane];
    {
        float r0 = 0.0f, r1 = 0.0f;
#pragma unroll
        for (int u = 0; u < 16; ++u) {
            r0 += E[0][u] * bl[u];
            r1 += E[1][u] * bl[u];
        }
        Ps[(rs * 2 + 0) * 64 + lane] = -p0;            // C = -Cl, p = rowsum(Cl)
        Rs[(rs * 2 + 0) * 64 + lane] = a0 * r0;
        Ps[(rs * 2 + 1) * 64 + lane] = -p1;
        Rs[(rs * 2 + 1) * 64 + lane] = a1 * r1;
    }
    __syncthreads();

    // G partial (this WG's 32 k-rows) -> atomicAdd into zeroed d_out
    float Rk[32];
#pragma unroll
    for (int k = 0; k < 32; ++k) Rk[k] = Rs[k * 64 + lane];  // B = lane
    const float sc = 1.0f / (256.0f * 1024.0f);
    float tsum = pad[tid & 2047];   // exact +0.0; keeps pad live
#pragma unroll
    for (int q = 0; q < 4; ++q) {
        int o = tid + 1024 * q;
        int A = o >> 6;  // = rs + 16*q
        float acc = 0.0f;
#pragma unroll
        for (int k = 0; k < 32; ++k) acc += Ps[k * 64 + A] * Rk[k];
        float val = acc * sc;
        atomicAdd(out + o, val);
        if (A == lane) tsum += val;
    }
#pragma unroll
    for (int m = 1; m < 64; m <<= 1) tsum += __shfl_xor(tsum, m, 64);
    if (lane == 0) twv[rs] = tsum;
    __syncthreads();
    if (tid == 0) {
        float ts = 0.0f;
#pragma unroll
        for (int w = 0; w < 16; ++w) ts += twv[w];
        atomicAdd(out + 4096, ts);
    }
}

// ---------------------------------------------------------------------------
extern "C" void kernel_launch(void* const* d_in, const int* in_sizes, int n_in,
                              void* d_out, int out_size, void* d_ws, size_t ws_size,
                              hipStream_t stream) {
    const float* X = (const float*)d_in[0];  // t_prob [1024,512]
    const float* Y = (const float*)d_in[1];  // v_prob [1024,512]
    float* out = (float*)d_out;              // [64*64 + 1]
    float* ws  = (float*)d_ws;

    // zero cvec + flags (tags rely on clean zeros; ws poisoned each call)
    (void)hipMemsetAsync((char*)d_ws + (size_t)CVEC_OFF * 4, 0,
                         (size_t)(3 * NWG * 1024 + 3 * NWG) * 4, stream);
    (void)hipMemsetAsync(d_out, 0, (size_t)out_size * 4, stream);

    k_gemm<<<dim3(16, 8), 256, 0, stream>>>(X, Y, ws);
    k_ipot<<<NWG, TPB, 0, stream>>>(ws, out);
}

// Round 8
// 2893.592 us; speedup vs baseline: 1.6722x; 1.6722x over previous
//
#include <hip/hip_runtime.h>
#include <math.h>

// ---------------------------------------------------------------------------
// IPOT on MI355X — round 13.
// Math (exact, verified in R1-R12):
//   Cl = -C;  M_t = exp((t+1)*Cl)
//   row:  r_i = sum_j M_t(i,j) s_j ; a = 1/(n r)
//   col:  c_j = sum_i M_t(i,j) a_i ; b = 1/c (2^10 inj); s' = b^2/b_prev/1024
//   final G(A,B) = (1/(256*1024)) sum_k P(k,A) R(k,B)
// R13 (R12's 2.27GB WRITE_SIZE = vals[32] scratch spill; 1024-thr blocks are
//      pinned at 64 VGPRs -> NO per-thread arrays. Protocol itself untested):
//   - Producers (R12): tagged per-WG plain stores (even t -> -v, odd -> +v;
//     partials > 0), advisory hint flag right after (NO drain barrier:
//     saves ~1 LLC RT/iter vs R11). 3-buffer rotation; tags are truth.
//   - Consumers: wave0 parks-and-polls the 32 hint flags (anti-storm gate);
//     then ALL threads do a one-shot 32-load running-sum readback with tag
//     check (ssum + allok bool only -- NOTHING TO SPILL); rare straggler ->
//     full re-read. Ascending slot order (absmax 0.0 in R8/R12).
//   - No zeroing pass (parity alternation); 384KB memset covers cvec+flags.
//   - k_gemm: R12's 128x64 tile / 8x4 micro / 256 thr (bit-identical C).
// ---------------------------------------------------------------------------

#define NWG 32
#define TPB 1024
#define NIT 50

typedef unsigned long long ull;

// ws offsets in floats
constexpr int CL_OFF   = 0;                           // -C [1024*1024]
constexpr int CVEC_OFF = 1024 * 1024;                 // [3][NWG][1024] tagged
constexpr int FLG_OFF  = CVEC_OFF + 3 * NWG * 1024;   // [3][NWG] tagged hints
// total ~ 4.6 MB

// ---------------- C = 1 - xhat yhat^T (norms fused) ; Cl = -C ---------------
__global__ __launch_bounds__(256, 1) void k_gemm(const float* __restrict__ X,
                                                 const float* __restrict__ Y,
                                                 float* __restrict__ ws) {
    __shared__ float As[32][132];   // X-tile, k-major, 128 rows
    __shared__ float Bs[32][68];    // Y-tile, k-major, 64 rows
    __shared__ float nX[128], nY[64];
    float* Cl = ws + CL_OFF;

    int tid = threadIdx.x;
    int tx = tid & 15, ty = tid >> 4;       // cols 4*tx, rows 8*ty
    int bx = blockIdx.x, by = blockIdx.y;   // bx 0..15 (64 cols), by 0..7 (128 rows)
    int sr = tid >> 3;                      // 0..31
    int kq = (tid & 7) * 4;                 // 0..28

    float acc[8][4] = {};
    float snx[4] = {0.f, 0.f, 0.f, 0.f};
    float sny0 = 0.f, sny1 = 0.f;
    for (int k0 = 0; k0 < 512; k0 += 32) {
        // stage X rows sr+32m (m<4) and Y rows sr, sr+32 at kq chunk
#pragma unroll
        for (int m = 0; m < 4; ++m) {
            int r = sr + 32 * m;
            float4 v = *(const float4*)(X + (size_t)(by * 128 + r) * 512 + k0 + kq);
            snx[m] += v.x * v.x + v.y * v.y + v.z * v.z + v.w * v.w;
            As[kq + 0][r] = v.x; As[kq + 1][r] = v.y;
            As[kq + 2][r] = v.z; As[kq + 3][r] = v.w;
        }
        {
            float4 v = *(const float4*)(Y + (size_t)(bx * 64 + sr) * 512 + k0 + kq);
            sny0 += v.x * v.x + v.y * v.y + v.z * v.z + v.w * v.w;
            Bs[kq + 0][sr] = v.x; Bs[kq + 1][sr] = v.y;
            Bs[kq + 2][sr] = v.z; Bs[kq + 3][sr] = v.w;
            float4 w = *(const float4*)(Y + (size_t)(bx * 64 + sr + 32) * 512 + k0 + kq);
            sny1 += w.x * w.x + w.y * w.y + w.z * w.z + w.w * w.w;
            Bs[kq + 0][sr + 32] = w.x; Bs[kq + 1][sr + 32] = w.y;
            Bs[kq + 2][sr + 32] = w.z; Bs[kq + 3][sr + 32] = w.w;
        }
        __syncthreads();
#pragma unroll
        for (int kk = 0; kk < 32; ++kk) {
            float4 a0 = *(const float4*)&As[kk][8 * ty];
            float4 a1 = *(const float4*)&As[kk][8 * ty + 4];
            float4 b0 = *(const float4*)&Bs[kk][4 * tx];
            float av[8] = {a0.x, a0.y, a0.z, a0.w, a1.x, a1.y, a1.z, a1.w};
            float bw[4] = {b0.x, b0.y, b0.z, b0.w};
#pragma unroll
            for (int r = 0; r < 8; ++r)
#pragma unroll
                for (int q = 0; q < 4; ++q) acc[r][q] += av[r] * bw[q];
        }
        __syncthreads();
    }
#pragma unroll
    for (int m2 = 1; m2 < 8; m2 <<= 1) {
#pragma unroll
        for (int m = 0; m < 4; ++m) snx[m] += __shfl_xor(snx[m], m2, 64);
        sny0 += __shfl_xor(sny0, m2, 64);
        sny1 += __shfl_xor(sny1, m2, 64);
    }
    if ((tid & 7) == 0) {
#pragma unroll
        for (int m = 0; m < 4; ++m) nX[sr + 32 * m] = snx[m];
        nY[sr] = sny0; nY[sr + 32] = sny1;
    }
    __syncthreads();

    float vy[4];
#pragma unroll
    for (int q = 0; q < 4; ++q) vy[q] = 1.0f / sqrtf(nY[4 * tx + q]);
    int i0 = by * 128 + 8 * ty, j0 = bx * 64 + 4 * tx;
#pragma unroll
    for (int r = 0; r < 8; ++r) {
        float vx = 1.0f / sqrtf(nX[8 * ty + r]);
        float4 o;
        o.x = acc[r][0] * vx * vy[0] - 1.0f;  // Cl = dot - 1 = -C
        o.y = acc[r][1] * vx * vy[1] - 1.0f;
        o.z = acc[r][2] * vx * vy[2] - 1.0f;
        o.w = acc[r][3] * vx * vy[3] - 1.0f;
        *(float4*)(Cl + (size_t)(i0 + r) * 1024 + j0) = o;
    }
}

// ---------------------- persistent IPOT iteration --------------------------
__global__ __launch_bounds__(1024)
void k_ipot(float* __restrict__ ws, float* __restrict__ out) {
    __shared__ float sLp[1056];        // s (loop) / b (epilogue): [u][l], stride 66
    __shared__ float buf[16 * 1056];   // col partials [wave][u*66+lane]; epi Ps/Rs
    __shared__ float twv[16];
    __shared__ float pad[2600];        // LDS > 80KB -> 1 WG/CU (occupancy shaper)

    const int g = blockIdx.x, tid = threadIdx.x;
    const int rs = tid >> 6, lane = tid & 63;   // wave id (0..15) / lane
    const int uo = tid & 15, lo = tid >> 4;     // owned col tid = lo*16+uo
    float* Cl   = ws + CL_OFF;
    float* cvec = ws + CVEC_OFF;
    float* flg  = ws + FLG_OFF;

    pad[tid & 2047] = 0.0f;  // keep pad allocated; read (exact +0.0) at end

    // thread owns rows g*32 + rs*2 + i (i<2), cols lane*16 + u (u<16)
    const float* csrc0 = Cl + (size_t)(g * 32 + rs * 2 + 0) * 1024 + lane * 16;
    const float* csrc1 = csrc0 + 1024;

    float E[2][16];
    float p0 = 0.0f, p1 = 0.0f;   // rowsum(Cl) for epilogue (C not kept)
#pragma unroll
    for (int q = 0; q < 4; ++q) {
        float4 c0 = *(const float4*)(csrc0 + 4 * q);
        float4 c1 = *(const float4*)(csrc1 + 4 * q);
        p0 += c0.x + c0.y + c0.z + c0.w;
        p1 += c1.x + c1.y + c1.z + c1.w;
        E[0][4 * q + 0] = __expf(c0.x); E[0][4 * q + 1] = __expf(c0.y);
        E[0][4 * q + 2] = __expf(c0.z); E[0][4 * q + 3] = __expf(c0.w);
        E[1][4 * q + 0] = __expf(c1.x); E[1][4 * q + 1] = __expf(c1.y);
        E[1][4 * q + 2] = __expf(c1.z); E[1][4 * q + 3] = __expf(c1.w);
    }

    float bv = 1.0f;            // b_prev for owned col (= tid)
    float a0 = 0.0f, a1 = 0.0f; // this wave's row scalings (all lanes)

    for (int t = 0; t < NIT; ++t) {
        float sval;
        if (t == 0) {
            sval = 1.0f / 1024.0f;
        } else {
            const int bsel = (t - 1) % 3;
            const bool expneg = ((t - 1) & 1) == 0;  // even iter stored -v
            // wave 0: advisory hint poll (parked economy); tags are truth
            if (rs == 0) {
                const float* fb = flg + bsel * NWG + (lane & 31);
                long gd = 0;
                for (;;) {
                    float v = __hip_atomic_load(fb, __ATOMIC_RELAXED,
                                                __HIP_MEMORY_SCOPE_AGENT);
                    bool ok = expneg ? (v < 0.0f) : (v > 0.0f);
                    if (__all(ok)) break;
                    if (++gd > 2000000) break;  // anti-hang bailout
                    __builtin_amdgcn_s_sleep(1);
                }
            }
            __syncthreads();
            // one-shot tag-checked running-sum readback (NO value array);
            // straggler -> full re-read (stateless, spill-proof)
            const float* rb = cvec + bsel * (NWG * 1024) + tid;
            float ssum = 0.0f;
            long gd = 0;
            for (;;) {
                ssum = 0.0f;
                unsigned bad = 0u;
#pragma unroll
                for (int s2 = 0; s2 < NWG; ++s2) {
                    float v = __hip_atomic_load(rb + s2 * 1024, __ATOMIC_RELAXED,
                                                __HIP_MEMORY_SCOPE_AGENT);
                    unsigned bits = __float_as_uint(v);
                    bad |= expneg ? (unsigned)(bits <= 0x80000000u)
                                  : (unsigned)(bits == 0u || bits >= 0x80000000u);
                    ssum += v;
                }
                if (!bad) break;
                if (++gd > 300000) break;  // anti-hang bailout
                __builtin_amdgcn_s_sleep(1);
            }
            float c = expneg ? -ssum : ssum;
            float b = 1.0f / c;
            sval = b * b / bv * (1.0f / 1024.0f);  // 2^-10 inj
            bv = b;
        }
        sLp[uo * 66 + lo] = sval;   // s for col tid at [tid&15][tid>>4]
        __syncthreads();

        // row phase: rp[i] = sum_u E[i][u] * s[lane*16+u]; xor-reduce -> all lanes
        float sv[16];
#pragma unroll
        for (int u = 0; u < 16; ++u) sv[u] = sLp[u * 66 + lane];
        float rp0 = 0.0f, rp1 = 0.0f;
#pragma unroll
        for (int u = 0; u < 16; ++u) {
            rp0 += E[0][u] * sv[u];
            rp1 += E[1][u] * sv[u];
        }
#pragma unroll
        for (int m = 1; m < 64; m <<= 1) {
            rp0 += __shfl_xor(rp0, m, 64);
            rp1 += __shfl_xor(rp1, m, 64);
        }
        a0 = 1.0f / (1024.0f * rp0);
        a1 = 1.0f / (1024.0f * rp1);

        // col phase: this wave's 2-row partials for its 16 cols (padded layout)
#pragma unroll
        for (int u = 0; u < 16; ++u)
            buf[rs * 1056 + u * 66 + lane] = E[0][u] * a0 + E[1][u] * a1;
        __syncthreads();

        // owner (col tid): sum 16 wave-partials, TAGGED store + hint (no drain)
        float csum = 0.0f;
#pragma unroll
        for (int w = 0; w < 16; ++w) csum += buf[w * 1056 + uo * 66 + lo];
        float tagged = (t & 1) ? csum : -csum;  // odd -> +, even -> -
        __hip_atomic_store(cvec + (t % 3) * (NWG * 1024) + g * 1024 + tid, tagged,
                           __ATOMIC_RELAXED, __HIP_MEMORY_SCOPE_AGENT);
        if (tid == 0)
            __hip_atomic_store(flg + (t % 3) * NWG + g, (t & 1) ? 1.0f : -1.0f,
                               __ATOMIC_RELAXED, __HIP_MEMORY_SCOPE_AGENT);

        // recompute E for next round: reload Cl (L2-hot) in the skew shadow
        if (t < NIT - 1) {
            const float kf = (float)(t + 2);
#pragma unroll
            for (int q = 0; q < 4; ++q) {
                float4 c0 = *(const float4*)(csrc0 + 4 * q);
                float4 c1 = *(const float4*)(csrc1 + 4 * q);
                E[0][4 * q + 0] = __expf(kf * c0.x); E[0][4 * q + 1] = __expf(kf * c0.y);
                E[0][4 * q + 2] = __expf(kf * c0.z); E[0][4 * q + 3] = __expf(kf * c0.w);
                E[1][4 * q + 0] = __expf(kf * c1.x); E[1][4 * q + 1] = __expf(kf * c1.y);
                E[1][4 * q + 2] = __expf(kf * c1.z); E[1][4 * q + 3] = __expf(kf * c1.w);
            }
        }
    }

    // ------------- epilogue: E = exp(50*Cl), a0/a1 = round-49 a -------------
    {
        const int bsel = (NIT - 1) % 3;      // iter 49, odd -> positive tags
        if (rs == 0) {
            const float* fb = flg + bsel * NWG + (lane & 31);
            long gd = 0;
            for (;;) {
                float v = __hip_atomic_load(fb, __ATOMIC_RELAXED,
                                            __HIP_MEMORY_SCOPE_AGENT);
                if (__all(v > 0.0f)) break;
                if (++gd > 2000000) break;
                __builtin_amdgcn_s_sleep(1);
            }
        }
        __syncthreads();
        const float* rb = cvec + bsel * (NWG * 1024) + tid;
        float ssum = 0.0f;
        long gd = 0;
        for (;;) {
            ssum = 0.0f;
            unsigned bad = 0u;
#pragma unroll
            for (int s2 = 0; s2 < NWG; ++s2) {
                float v = __hip_atomic_load(rb + s2 * 1024, __ATOMIC_RELAXED,
                                            __HIP_MEMORY_SCOPE_AGENT);
                unsigned bits = __float_as_uint(v);
                bad |= (unsigned)(bits == 0u || bits >= 0x80000000u);
                ssum += v;
            }
            if (!bad) break;
            if (++gd > 300000) break;
            __builtin_amdgcn_s_sleep(1);
        }
        sLp[uo * 66 + lo] = 1.0f / ssum;   // b for col tid
    }
    __syncthreads();

    // P(k,A=lane) and R(k,B=lane) for this thread's 2 rows (A-block == lane)
    float* Ps = buf;          // [32][64]
    float* Rs = buf + 2048;   // [32][64]
    float bl[16];
#pragma unroll
    for (int u = 0; u < 16; ++u) bl[u] = sLp[u * 66 + lane];
    {
        float r0 = 0.0f, r1 = 0.0f;
#pragma unroll
        for (int u = 0; u < 16; ++u) {
            r0 += E[0][u] * bl[u];
            r1 += E[1][u] * bl[u];
        }
        Ps[(rs * 2 + 0) * 64 + lane] = -p0;            // C = -Cl, p = rowsum(Cl)
        Rs[(rs * 2 + 0) * 64 + lane] = a0 * r0;
        Ps[(rs * 2 + 1) * 64 + lane] = -p1;
        Rs[(rs * 2 + 1) * 64 + lane] = a1 * r1;
    }
    __syncthreads();

    // G partial (this WG's 32 k-rows) -> atomicAdd into zeroed d_out
    float Rk[32];
#pragma unroll
    for (int k = 0; k < 32; ++k) Rk[k] = Rs[k * 64 + lane];  // B = lane
    const float sc = 1.0f / (256.0f * 1024.0f);
    float tsum = pad[tid & 2047];   // exact +0.0; keeps pad live
#pragma unroll
    for (int q = 0; q < 4; ++q) {
        int o = tid + 1024 * q;
        int A = o >> 6;  // = rs + 16*q
        float acc = 0.0f;
#pragma unroll
        for (int k = 0; k < 32; ++k) acc += Ps[k * 64 + A] * Rk[k];
        float val = acc * sc;
        atomicAdd(out + o, val);
        if (A == lane) tsum += val;
    }
#pragma unroll
    for (int m = 1; m < 64; m <<= 1) tsum += __shfl_xor(tsum, m, 64);
    if (lane == 0) twv[rs] = tsum;
    __syncthreads();
    if (tid == 0) {
        float ts = 0.0f;
#pragma unroll
        for (int w = 0; w < 16; ++w) ts += twv[w];
        atomicAdd(out + 4096, ts);
    }
}

// ---------------------------------------------------------------------------
extern "C" void kernel_launch(void* const* d_in, const int* in_sizes, int n_in,
                              void* d_out, int out_size, void* d_ws, size_t ws_size,
                              hipStream_t stream) {
    const float* X = (const float*)d_in[0];  // t_prob [1024,512]
    const float* Y = (const float*)d_in[1];  // v_prob [1024,512]
    float* out = (float*)d_out;              // [64*64 + 1]
    float* ws  = (float*)d_ws;

    // zero cvec + flags (tags rely on clean zeros; ws poisoned each call)
    (void)hipMemsetAsync((char*)d_ws + (size_t)CVEC_OFF * 4, 0,
                         (size_t)(3 * NWG * 1024 + 3 * NWG) * 4, stream);
    (void)hipMemsetAsync(d_out, 0, (size_t)out_size * 4, stream);

    k_gemm<<<dim3(16, 8), 256, 0, stream>>>(X, Y, ws);
    k_ipot<<<NWG, TPB, 0, stream>>>(ws, out);
}